// Round 13
// baseline (233.306 us; speedup 1.0000x reference)
//
#include <hip/hip_runtime.h>
#include <hip/hip_bf16.h>

typedef unsigned short u16;
typedef unsigned int u32;
typedef __attribute__((ext_vector_type(8))) short short8;
typedef __attribute__((ext_vector_type(4))) float f32x4;
typedef __attribute__((ext_vector_type(4))) unsigned int u32x4;

#define B_SZ 16
#define S_SZ 512
#define D_SZ 1024
#define H_SZ 16
#define DH_SZ 64
#define M_SZ (B_SZ * S_SZ)      // 8192
#define EXPSCALE 0.18033688f    // 0.125 * log2(e)

// direct global->LDS DMA, 16B per lane; LDS dest = wave-uniform base + lane*16
__device__ __forceinline__ void gload_lds16(const void* g, void* l) {
  __builtin_amdgcn_global_load_lds(
      (const __attribute__((address_space(1))) unsigned int*)g,
      (__attribute__((address_space(3))) unsigned int*)l,
      16, 0, 0);
}

__device__ __forceinline__ u16 bf16b(float x) {
  __hip_bfloat16 h = __float2bfloat16(x);
  return *(u16*)&h;
}

// ---------------------------------------------------------------------------
// prep: fused f32->bf16 cast of v (blocks 0..8191) + weight transpose+downcast
// ---------------------------------------------------------------------------
__global__ __launch_bounds__(256) void prep(
    const float* __restrict__ v, u16* __restrict__ vB,
    const float* __restrict__ W0, const float* __restrict__ W1,
    const float* __restrict__ W2, const float* __restrict__ W3,
    u16* __restrict__ T0, u16* __restrict__ T1,
    u16* __restrict__ T2, u16* __restrict__ T3) {
  __shared__ float tile[32][33];
  const int bid = blockIdx.x;
  if (bid < 8192) {
    int i = bid * 256 + threadIdx.x;
    const float4 f = *(const float4*)&v[(size_t)i * 4];
    ushort4 o;
    o.x = bf16b(f.x); o.y = bf16b(f.y); o.z = bf16b(f.z); o.w = bf16b(f.w);
    *(ushort4*)&vB[(size_t)i * 4] = o;
    return;
  }
  const int tb = bid - 8192;
  const int z = tb >> 10, rem = tb & 1023;
  const int by = rem >> 5, bx = rem & 31;
  const float* W; u16* T;
  switch (z) {
    case 0: W = W0; T = T0; break;
    case 1: W = W1; T = T1; break;
    case 2: W = W2; T = T2; break;
    default: W = W3; T = T3; break;
  }
  int tx = threadIdx.x & 31, ty = threadIdx.x >> 5;  // 32 x 8
  int x = bx * 32 + tx;
#pragma unroll
  for (int i = 0; i < 32; i += 8)
    tile[ty + i][tx] = W[(size_t)(by * 32 + ty + i) * 1024 + x];
  __syncthreads();
  int x2 = by * 32 + tx;
#pragma unroll
  for (int i = 0; i < 32; i += 8)
    T[(size_t)(bx * 32 + ty + i) * 1024 + x2] = bf16b(tile[tx][ty + i]);
}

// ---------------------------------------------------------------------------
// GEMM core v3 (LOCKED, session best): BM=128 BN=256 BK=64, 8 waves
// (2M x 4N, 64x64 per wave), 3 LDS buffers, prefetch distance 2, counted
// s_waitcnt vmcnt(6), single-phase K-tile with ONE barrier.  16B-granule
// XOR swizzle on pre-swizzled global source + ds_read addr.
// ---------------------------------------------------------------------------
struct G8 {
  const u16* A; const u16* Bt;
  u16* As; u16* Bs;               // base of As[0], Bs[0]
  int m0, n0;
  int wave, c, quad, r7, wm, wn;
  int srow, slc8;                 // staging geometry
};

#define AS_T (128 * 64)           // elems per A buffer
#define BS_T (256 * 64)           // elems per B buffer

__device__ __forceinline__ void stage_a(const G8& g, int buf, int kt, int i) {
  const int grp = g.wave * 2 + i;                       // 16 groups of 8 rows
  gload_lds16(&g.A[(size_t)(g.m0 + grp * 8 + g.srow) * 1024 + kt * 64 + g.slc8],
              g.As + buf * AS_T + grp * 512);
}
__device__ __forceinline__ void stage_b(const G8& g, int buf, int kt, int i) {
  const int grp = g.wave * 4 + i;                       // 32 groups of 8 rows
  gload_lds16(&g.Bt[(size_t)(g.n0 + grp * 8 + g.srow) * 1024 + kt * 64 + g.slc8],
              g.Bs + buf * BS_T + grp * 512);
}

template<bool ST, int VM>
__device__ __forceinline__ void tile_step(const G8& g, int cur, int stg, int kt2,
                                          f32x4 acc[4][4]) {
  const u16* ab = g.As + cur * AS_T;
  const u16* bb = g.Bs + cur * BS_T;
  short8 af0[4], bf0[4], af1[4], bf1[4];

  const int pc0 = (g.quad ^ g.r7) * 8;
  const int pc1 = ((4 + g.quad) ^ g.r7) * 8;
#pragma unroll
  for (int i = 0; i < 4; ++i) {
    af0[i] = *(const short8*)&ab[(g.wm + i * 16 + g.c) * 64 + pc0];
    bf0[i] = *(const short8*)&bb[(g.wn + i * 16 + g.c) * 64 + pc0];
    af1[i] = *(const short8*)&ab[(g.wm + i * 16 + g.c) * 64 + pc1];
    bf1[i] = *(const short8*)&bb[(g.wn + i * 16 + g.c) * 64 + pc1];
  }
  if constexpr (ST) {
    stage_a(g, stg, kt2, 0);
    stage_a(g, stg, kt2, 1);
    stage_b(g, stg, kt2, 0);
    stage_b(g, stg, kt2, 1);
    stage_b(g, stg, kt2, 2);
    stage_b(g, stg, kt2, 3);
  }
  __builtin_amdgcn_s_setprio(1);
#pragma unroll
  for (int mi = 0; mi < 4; ++mi)
#pragma unroll
    for (int ni = 0; ni < 4; ++ni)
      acc[mi][ni] = __builtin_amdgcn_mfma_f32_16x16x32_bf16(
          af0[mi], bf0[ni], acc[mi][ni], 0, 0, 0);
#pragma unroll
  for (int mi = 0; mi < 4; ++mi)
#pragma unroll
    for (int ni = 0; ni < 4; ++ni)
      acc[mi][ni] = __builtin_amdgcn_mfma_f32_16x16x32_bf16(
          af1[mi], bf1[ni], acc[mi][ni], 0, 0, 0);
  __builtin_amdgcn_s_setprio(0);
  if constexpr (VM == 6) {
    asm volatile("s_waitcnt vmcnt(6)" ::: "memory");
    __builtin_amdgcn_s_barrier();
  } else if constexpr (VM == 0) {
    asm volatile("s_waitcnt vmcnt(0)" ::: "memory");
    __builtin_amdgcn_s_barrier();
  }
  // VM == -1: last tile, no wait / no trailing barrier
}

__device__ __forceinline__ void gemm_core8(
    const u16* __restrict__ A, const u16* __restrict__ Bt,
    u16* AsB, u16* BsB, int m0, int n0, f32x4 acc[4][4]) {
  const int tid = threadIdx.x;
  const int lane = tid & 63;
  G8 g;
  g.A = A; g.Bt = Bt; g.As = AsB; g.Bs = BsB;
  g.m0 = m0; g.n0 = n0;
  g.wave = tid >> 6;
  g.c = lane & 15; g.quad = lane >> 4; g.r7 = g.c & 7;
  g.wm = (g.wave >> 2) * 64;          // 2 wave-rows
  g.wn = (g.wave & 3) * 64;           // 4 wave-cols
  g.srow = lane >> 3;                 // 0..7 within 8-row DMA group
  g.slc8 = ((lane & 7) ^ g.srow) * 8; // pre-swizzled source column (elems)

  // prologue: stage K-tiles 0 and 1 (6 loads each, per wave)
  stage_a(g, 0, 0, 0); stage_a(g, 0, 0, 1);
  stage_b(g, 0, 0, 0); stage_b(g, 0, 0, 1); stage_b(g, 0, 0, 2); stage_b(g, 0, 0, 3);
  stage_a(g, 1, 1, 0); stage_a(g, 1, 1, 1);
  stage_b(g, 1, 1, 0); stage_b(g, 1, 1, 1); stage_b(g, 1, 1, 2); stage_b(g, 1, 1, 3);
  asm volatile("s_waitcnt vmcnt(6)" ::: "memory");   // tile 0 resident, tile 1 in flight
  __builtin_amdgcn_s_barrier();

  int cur = 0, stg = 2;
#pragma unroll 1
  for (int t = 0; t < 14; ++t) {      // K/64 = 16 tiles; 14 steady-state iters
    tile_step<true, 6>(g, cur, stg, t + 2, acc);
    cur = (cur == 2) ? 0 : cur + 1;
    stg = (stg == 2) ? 0 : stg + 1;
  }
  tile_step<false, 0>(g, cur, 0, 0, acc);   // tile 14 (cur=2): drain tile 15
  tile_step<false, -1>(g, 0, 0, 0, acc);    // tile 15 (cur=0): final
}

// ---------------------------------------------------------------------------
// Fused QKV GEMM.  Grid (64 m, 4 n, 3 z).  z=0: Q (row-major, PRE-SCALED by
// EXPSCALE), z=1: K ([b,h,s,d]), z=2: V ([b,h,d,s]).
// LENGTH SKIP: K/V blocks whose whole 128-row range is >= ceil(len/64)*64
// exit before any staging/barrier (rows never read by attn's key mask).
// ---------------------------------------------------------------------------
__global__ __launch_bounds__(512, 2) void gemm_qkv(
    const u16* __restrict__ A,
    const u16* __restrict__ BtQ, const u16* __restrict__ BtK, const u16* __restrict__ BtV,
    const float* __restrict__ bq, const float* __restrict__ bk, const float* __restrict__ bv,
    const int* __restrict__ lengths,
    u16* __restrict__ Qo, u16* __restrict__ Kt, u16* __restrict__ Vt) {
  __shared__ u16 As[3][AS_T];
  __shared__ u16 Bs[3][BS_T];
  const int z = blockIdx.z;
  const int m0 = blockIdx.x * 128, n0 = blockIdx.y * 256;

  if (z != 0) {
    const int bb = m0 >> 9, s0 = m0 & 511;
    const int kmaxb = (lengths[bb] + 63) & ~63;
    if (s0 >= kmaxb) return;        // dead K/V rows: uniform exit, no barriers yet
  }

  const u16* Bt = (z == 0) ? BtQ : (z == 1) ? BtK : BtV;
  const float* bias = (z == 0) ? bq : (z == 1) ? bk : bv;

  f32x4 acc[4][4];
#pragma unroll
  for (int i = 0; i < 4; ++i)
#pragma unroll
    for (int j = 0; j < 4; ++j) acc[i][j] = f32x4{0.f, 0.f, 0.f, 0.f};

  gemm_core8(A, Bt, &As[0][0], &Bs[0][0], m0, n0, acc);

  const int lane = threadIdx.x & 63, wave = threadIdx.x >> 6;
  const int wm = (wave >> 2) * 64, wn = (wave & 3) * 64;
  const int c = lane & 15, quad = lane >> 4;
#pragma unroll
  for (int ni = 0; ni < 4; ++ni) {
    int n = n0 + wn + ni * 16 + c;
    float bval = bias[n];
#pragma unroll
    for (int mi = 0; mi < 4; ++mi) {
      int mb = m0 + wm + mi * 16 + quad * 4;
      if (z == 2) {
        int bb = mb >> 9, s = mb & 511, hh = n >> 6, d = n & 63;
        ushort4 st;
        st.x = bf16b(acc[mi][ni][0] + bval);
        st.y = bf16b(acc[mi][ni][1] + bval);
        st.z = bf16b(acc[mi][ni][2] + bval);
        st.w = bf16b(acc[mi][ni][3] + bval);
        *(ushort4*)&Vt[(((size_t)(bb * 16 + hh) * 64 + d) << 9) + s] = st;
      } else if (z == 0) {
#pragma unroll
        for (int r = 0; r < 4; ++r) {
          int m = mb + r;
          Qo[(size_t)m * 1024 + n] = bf16b((acc[mi][ni][r] + bval) * EXPSCALE);
        }
      } else {
#pragma unroll
        for (int r = 0; r < 4; ++r) {
          int m = mb + r;
          int bb = m >> 9, s = m & 511, hh = n >> 6, d = n & 63;
          Kt[(((size_t)(bb * 16 + hh) * 512 + s) << 6) + d] = bf16b(acc[mi][ni][r] + bval);
        }
      }
    }
  }
}

// ---------------------------------------------------------------------------
// Output GEMM: C_f32 = A @ Bt^T + bias.  Grid (64 m, 4 n) = 256 blocks.
// ---------------------------------------------------------------------------
__global__ __launch_bounds__(512, 2) void gemm_out(
    const u16* __restrict__ A, const u16* __restrict__ Bt,
    const float* __restrict__ bias, float* __restrict__ Cf) {
  __shared__ u16 As[3][AS_T];
  __shared__ u16 Bs[3][BS_T];
  const int m0 = blockIdx.x * 128, n0 = blockIdx.y * 256;

  f32x4 acc[4][4];
#pragma unroll
  for (int i = 0; i < 4; ++i)
#pragma unroll
    for (int j = 0; j < 4; ++j) acc[i][j] = f32x4{0.f, 0.f, 0.f, 0.f};

  gemm_core8(A, Bt, &As[0][0], &Bs[0][0], m0, n0, acc);

  const int lane = threadIdx.x & 63, wave = threadIdx.x >> 6;
  const int wm = (wave >> 2) * 64, wn = (wave & 3) * 64;
  const int c = lane & 15, quad = lane >> 4;
#pragma unroll
  for (int ni = 0; ni < 4; ++ni) {
    int n = n0 + wn + ni * 16 + c;
    float bval = bias[n];
#pragma unroll
    for (int mi = 0; mi < 4; ++mi) {
#pragma unroll
      for (int r = 0; r < 4; ++r) {
        int m = m0 + wm + mi * 16 + quad * 4 + r;
        Cf[(size_t)m * 1024 + n] = acc[mi][ni][r] + bval;
      }
    }
  }
}

// ---------------------------------------------------------------------------
// Attention v11: NO LDS, NO BARRIERS — direct per-lane global K/V loads
// (Common-mistake #7 / m169: K/V per (b,h) is 128 KB, L2-resident; LDS
// staging + per-tile __syncthreads was the serialization v7/v8/v10 couldn't
// remove).  The staging key-permutation and chunk swizzle fold into the
// load addresses; MFMA inputs are identical values in identical order ->
// bit-identical output vs v9/v10.
// Grid (4 qchunks, 16 heads, 16 batches); wave = 32 q rows, 4 waves/block.
// ---------------------------------------------------------------------------
__global__ __launch_bounds__(256) void attn_v11(
    const u16* __restrict__ Q, const u16* __restrict__ Kt,
    const u16* __restrict__ Vt, const int* __restrict__ lengths,
    u16* __restrict__ O) {
  const int qc = blockIdx.x, h = blockIdx.y, b = blockIdx.z;
  const int t = threadIdx.x;
  const int lane = t & 63, wave = t >> 6;
  const int c = lane & 15, quad = lane >> 4;
  const int len = lengths[b];
  const int q0 = qc * 128 + wave * 32;          // 32 q-rows per wave

  const size_t bBase = (size_t)b * (S_SZ * D_SZ);
  const size_t hBase = ((size_t)(b * H_SZ + h)) * (S_SZ * DH_SZ);

  short8 aq[2][2];
#pragma unroll
  for (int qt = 0; qt < 2; ++qt) {
    aq[qt][0] = *(const short8*)&Q[bBase + (size_t)(q0 + qt * 16 + c) * 1024 + h * 64 + quad * 8];
    aq[qt][1] = *(const short8*)&Q[bBase + (size_t)(q0 + qt * 16 + c) * 1024 + h * 64 + 32 + quad * 8];
  }

  // all-ones bf16 fragment for the row-sum MFMA
  const short ONE = (short)0x3F80;
  const short8 ones = {ONE, ONE, ONE, ONE, ONE, ONE, ONE, ONE};

  f32x4 o[2][4];
  f32x4 osum[2];
#pragma unroll
  for (int qt = 0; qt < 2; ++qt) {
    osum[qt] = f32x4{0.f, 0.f, 0.f, 0.f};
#pragma unroll
    for (int i = 0; i < 4; ++i) o[qt][i] = f32x4{0.f, 0.f, 0.f, 0.f};
  }

  const int kmax = (len + 63) & ~63;
#pragma unroll 1
  for (int k0 = 0; k0 < kmax; k0 += 64) {
    const bool full = (k0 + 64 <= len);       // wave-uniform

#pragma unroll
    for (int half = 0; half < 2; ++half) {    // half == ksub
      u32 pk[2][4];                           // [qt][4 u32 = 8 bf16 P values]
      // --- S^T for sub = half and sub = half+2 (sources of pa(half)) ---
#pragma unroll
      for (int ss = 0; ss < 2; ++ss) {
        const int sub = half + ss * 2;
        const int row = sub * 16 + c;         // 0..63
        // key permutation (was the staging row permutation):
        // grow = row[4]*32 + row[3:2]*8 + row[5]*4 + row[1:0]
        const int grow = ((row >> 4) & 1) * 32 + ((row >> 2) & 3) * 8 +
                         ((row >> 5) & 1) * 4 + (row & 3);
        const u16* kp = &Kt[hBase + (size_t)(k0 + grow) * 64];
        short8 bk0 = *(const short8*)&kp[quad * 8];        // chunk = quad
        short8 bk1 = *(const short8*)&kp[32 + quad * 8];   // chunk = 4+quad
        // permuted key base for this lane's 4 output rows
        const int keyb = k0 + (sub & 1) * 32 + quad * 8 + (sub >> 1) * 4;
#pragma unroll
        for (int qt = 0; qt < 2; ++qt) {
          f32x4 s = {0.f, 0.f, 0.f, 0.f};
          s = __builtin_amdgcn_mfma_f32_16x16x32_bf16(bk0, aq[qt][0], s, 0, 0, 0);
          s = __builtin_amdgcn_mfma_f32_16x16x32_bf16(bk1, aq[qt][1], s, 0, 0, 0);
          float p0, p1, p2, p3;
          if (full) {
            p0 = exp2f(s[0]); p1 = exp2f(s[1]);
            p2 = exp2f(s[2]); p3 = exp2f(s[3]);
          } else {
            p0 = (keyb + 0) < len ? exp2f(s[0]) : 0.f;
            p1 = (keyb + 1) < len ? exp2f(s[1]) : 0.f;
            p2 = (keyb + 2) < len ? exp2f(s[2]) : 0.f;
            p3 = (keyb + 3) < len ? exp2f(s[3]) : 0.f;
          }
          pk[qt][ss * 2 + 0] = (u32)bf16b(p0) | ((u32)bf16b(p1) << 16);
          pk[qt][ss * 2 + 1] = (u32)bf16b(p2) | ((u32)bf16b(p3) << 16);
        }
      }
      // --- PV for ksub = half: pa from own registers, V direct from L2 ---
      u32x4 w0 = {pk[0][0], pk[0][1], pk[0][2], pk[0][3]};
      u32x4 w1 = {pk[1][0], pk[1][1], pk[1][2], pk[1][3]};
      short8 pa0, pa1;
      __builtin_memcpy(&pa0, &w0, 16);
      __builtin_memcpy(&pa1, &w1, 16);
      osum[0] = __builtin_amdgcn_mfma_f32_16x16x32_bf16(pa0, ones, osum[0], 0, 0, 0);
      osum[1] = __builtin_amdgcn_mfma_f32_16x16x32_bf16(pa1, ones, osum[1], 0, 0, 0);
#pragma unroll
      for (int dt = 0; dt < 4; ++dt) {
        short8 vb = *(const short8*)&Vt[hBase + (size_t)(dt * 16 + c) * 512 +
                                        k0 + (half * 4 + quad) * 8];
        o[0][dt] = __builtin_amdgcn_mfma_f32_16x16x32_bf16(pa0, vb, o[0][dt], 0, 0, 0);
        o[1][dt] = __builtin_amdgcn_mfma_f32_16x16x32_bf16(pa1, vb, o[1][dt], 0, 0, 0);
      }
    }
  }

  // --- epilogue: osum[qt][r] is the row-sum for exactly the q-row of
  //     o[qt][dt][r] (same accumulator layout) -> direct divide. ---
#pragma unroll
  for (int qt = 0; qt < 2; ++qt) {
    float inv[4];
#pragma unroll
    for (int r = 0; r < 4; ++r) inv[r] = 1.0f / osum[qt][r];
#pragma unroll
    for (int dt = 0; dt < 4; ++dt) {
#pragma unroll
      for (int r = 0; r < 4; ++r) {
        int s = q0 + qt * 16 + quad * 4 + r;
        float val = o[qt][dt][r] * inv[r];
        O[bBase + (size_t)s * 1024 + h * 64 + dt * 16 + c] = bf16b(val);
      }
    }
  }
}

// ---------------------------------------------------------------------------
extern "C" void kernel_launch(void* const* d_in, const int* in_sizes, int n_in,
                              void* d_out, int out_size, void* d_ws, size_t ws_size,
                              hipStream_t stream) {
  const float* v  = (const float*)d_in[0];
  const int* lengths = (const int*)d_in[1];
  const float* Wq = (const float*)d_in[2];
  const float* bq = (const float*)d_in[3];
  const float* Wk = (const float*)d_in[4];
  const float* bk = (const float*)d_in[5];
  const float* Wv = (const float*)d_in[6];
  const float* bv = (const float*)d_in[7];
  const float* Wo = (const float*)d_in[8];
  const float* bo = (const float*)d_in[9];

  char* ws = (char*)d_ws;
  const size_t TSZ = (size_t)M_SZ * D_SZ * 2;   // 16 MiB bf16 activation tensor
  const size_t WSZ = (size_t)1 << 21;           // 2 MiB per transposed weight
  u16* vB  = (u16*)(ws);                        // aliased: AO reuses this after QKV
  u16* AO  = vB;
  u16* WqT = (u16*)(ws + TSZ + 0 * WSZ);
  u16* WkT = (u16*)(ws + TSZ + 1 * WSZ);
  u16* WvT = (u16*)(ws + TSZ + 2 * WSZ);
  u16* WoT = (u16*)(ws + TSZ + 3 * WSZ);
  u16* Qb  = (u16*)(ws + TSZ + 4 * WSZ + 0 * TSZ);
  u16* Kt  = (u16*)(ws + TSZ + 4 * WSZ + 1 * TSZ);
  u16* Vt  = (u16*)(ws + TSZ + 4 * WSZ + 2 * TSZ);

  prep<<<dim3(8192 + 4096), 256, 0, stream>>>(v, vB, Wq, Wk, Wv, Wo, WqT, WkT, WvT, WoT);

  gemm_qkv<<<dim3(64, 4, 3), 512, 0, stream>>>(vB, WqT, WkT, WvT, bq, bk, bv, lengths, Qb, Kt, Vt);

  attn_v11<<<dim3(4, 16, 16), 256, 0, stream>>>(Qb, Kt, Vt, lengths, AO);

  gemm_out<<<dim3(64, 4), 512, 0, stream>>>(AO, WoT, bo, (float*)d_out);
}

// Round 14
// 213.751 us; speedup vs baseline: 1.0915x; 1.0915x over previous
//
#include <hip/hip_runtime.h>
#include <hip/hip_bf16.h>

typedef unsigned short u16;
typedef unsigned int u32;
typedef __attribute__((ext_vector_type(8))) short short8;
typedef __attribute__((ext_vector_type(4))) float f32x4;
typedef __attribute__((ext_vector_type(4))) unsigned int u32x4;

#define B_SZ 16
#define S_SZ 512
#define D_SZ 1024
#define H_SZ 16
#define DH_SZ 64
#define M_SZ (B_SZ * S_SZ)      // 8192
#define EXPSCALE 0.18033688f    // 0.125 * log2(e)

// direct global->LDS DMA, 16B per lane; LDS dest = wave-uniform base + lane*16
__device__ __forceinline__ void gload_lds16(const void* g, void* l) {
  __builtin_amdgcn_global_load_lds(
      (const __attribute__((address_space(1))) unsigned int*)g,
      (__attribute__((address_space(3))) unsigned int*)l,
      16, 0, 0);
}

__device__ __forceinline__ u16 bf16b(float x) {
  __hip_bfloat16 h = __float2bfloat16(x);
  return *(u16*)&h;
}

// ---------------------------------------------------------------------------
// prep: fused f32->bf16 cast of v (blocks 0..8191) + weight transpose+downcast
// ---------------------------------------------------------------------------
__global__ __launch_bounds__(256) void prep(
    const float* __restrict__ v, u16* __restrict__ vB,
    const float* __restrict__ W0, const float* __restrict__ W1,
    const float* __restrict__ W2, const float* __restrict__ W3,
    u16* __restrict__ T0, u16* __restrict__ T1,
    u16* __restrict__ T2, u16* __restrict__ T3) {
  __shared__ float tile[32][33];
  const int bid = blockIdx.x;
  if (bid < 8192) {
    int i = bid * 256 + threadIdx.x;
    const float4 f = *(const float4*)&v[(size_t)i * 4];
    ushort4 o;
    o.x = bf16b(f.x); o.y = bf16b(f.y); o.z = bf16b(f.z); o.w = bf16b(f.w);
    *(ushort4*)&vB[(size_t)i * 4] = o;
    return;
  }
  const int tb = bid - 8192;
  const int z = tb >> 10, rem = tb & 1023;
  const int by = rem >> 5, bx = rem & 31;
  const float* W; u16* T;
  switch (z) {
    case 0: W = W0; T = T0; break;
    case 1: W = W1; T = T1; break;
    case 2: W = W2; T = T2; break;
    default: W = W3; T = T3; break;
  }
  int tx = threadIdx.x & 31, ty = threadIdx.x >> 5;  // 32 x 8
  int x = bx * 32 + tx;
#pragma unroll
  for (int i = 0; i < 32; i += 8)
    tile[ty + i][tx] = W[(size_t)(by * 32 + ty + i) * 1024 + x];
  __syncthreads();
  int x2 = by * 32 + tx;
#pragma unroll
  for (int i = 0; i < 32; i += 8)
    T[(size_t)(bx * 32 + ty + i) * 1024 + x2] = bf16b(tile[tx][ty + i]);
}

// ---------------------------------------------------------------------------
// GEMM core v3 (LOCKED, session best): BM=128 BN=256 BK=64, 8 waves
// (2M x 4N, 64x64 per wave), 3 LDS buffers, prefetch distance 2, counted
// s_waitcnt vmcnt(6), single-phase K-tile with ONE barrier.  16B-granule
// XOR swizzle on pre-swizzled global source + ds_read addr (0 conflicts).
// Excursions that REGRESSED (do not retry): BK=32 2-blk/CU (r10 +10us),
// 256-square single-phase (r11 +15us), 2-phase-per-tile (r1 +5us).
// ---------------------------------------------------------------------------
struct G8 {
  const u16* A; const u16* Bt;
  u16* As; u16* Bs;               // base of As[0], Bs[0]
  int m0, n0;
  int wave, c, quad, r7, wm, wn;
  int srow, slc8;                 // staging geometry
};

#define AS_T (128 * 64)           // elems per A buffer
#define BS_T (256 * 64)           // elems per B buffer

__device__ __forceinline__ void stage_a(const G8& g, int buf, int kt, int i) {
  const int grp = g.wave * 2 + i;                       // 16 groups of 8 rows
  gload_lds16(&g.A[(size_t)(g.m0 + grp * 8 + g.srow) * 1024 + kt * 64 + g.slc8],
              g.As + buf * AS_T + grp * 512);
}
__device__ __forceinline__ void stage_b(const G8& g, int buf, int kt, int i) {
  const int grp = g.wave * 4 + i;                       // 32 groups of 8 rows
  gload_lds16(&g.Bt[(size_t)(g.n0 + grp * 8 + g.srow) * 1024 + kt * 64 + g.slc8],
              g.Bs + buf * BS_T + grp * 512);
}

template<bool ST, int VM>
__device__ __forceinline__ void tile_step(const G8& g, int cur, int stg, int kt2,
                                          f32x4 acc[4][4]) {
  const u16* ab = g.As + cur * AS_T;
  const u16* bb = g.Bs + cur * BS_T;
  short8 af0[4], bf0[4], af1[4], bf1[4];

  const int pc0 = (g.quad ^ g.r7) * 8;
  const int pc1 = ((4 + g.quad) ^ g.r7) * 8;
#pragma unroll
  for (int i = 0; i < 4; ++i) {
    af0[i] = *(const short8*)&ab[(g.wm + i * 16 + g.c) * 64 + pc0];
    bf0[i] = *(const short8*)&bb[(g.wn + i * 16 + g.c) * 64 + pc0];
    af1[i] = *(const short8*)&ab[(g.wm + i * 16 + g.c) * 64 + pc1];
    bf1[i] = *(const short8*)&bb[(g.wn + i * 16 + g.c) * 64 + pc1];
  }
  if constexpr (ST) {
    stage_a(g, stg, kt2, 0);
    stage_a(g, stg, kt2, 1);
    stage_b(g, stg, kt2, 0);
    stage_b(g, stg, kt2, 1);
    stage_b(g, stg, kt2, 2);
    stage_b(g, stg, kt2, 3);
  }
  __builtin_amdgcn_s_setprio(1);
#pragma unroll
  for (int mi = 0; mi < 4; ++mi)
#pragma unroll
    for (int ni = 0; ni < 4; ++ni)
      acc[mi][ni] = __builtin_amdgcn_mfma_f32_16x16x32_bf16(
          af0[mi], bf0[ni], acc[mi][ni], 0, 0, 0);
#pragma unroll
  for (int mi = 0; mi < 4; ++mi)
#pragma unroll
    for (int ni = 0; ni < 4; ++ni)
      acc[mi][ni] = __builtin_amdgcn_mfma_f32_16x16x32_bf16(
          af1[mi], bf1[ni], acc[mi][ni], 0, 0, 0);
  __builtin_amdgcn_s_setprio(0);
  if constexpr (VM == 6) {
    asm volatile("s_waitcnt vmcnt(6)" ::: "memory");
    __builtin_amdgcn_s_barrier();
  } else if constexpr (VM == 0) {
    asm volatile("s_waitcnt vmcnt(0)" ::: "memory");
    __builtin_amdgcn_s_barrier();
  }
  // VM == -1: last tile, no wait / no trailing barrier
}

__device__ __forceinline__ void gemm_core8(
    const u16* __restrict__ A, const u16* __restrict__ Bt,
    u16* AsB, u16* BsB, int m0, int n0, f32x4 acc[4][4]) {
  const int tid = threadIdx.x;
  const int lane = tid & 63;
  G8 g;
  g.A = A; g.Bt = Bt; g.As = AsB; g.Bs = BsB;
  g.m0 = m0; g.n0 = n0;
  g.wave = tid >> 6;
  g.c = lane & 15; g.quad = lane >> 4; g.r7 = g.c & 7;
  g.wm = (g.wave >> 2) * 64;          // 2 wave-rows
  g.wn = (g.wave & 3) * 64;           // 4 wave-cols
  g.srow = lane >> 3;                 // 0..7 within 8-row DMA group
  g.slc8 = ((lane & 7) ^ g.srow) * 8; // pre-swizzled source column (elems)

  // prologue: stage K-tiles 0 and 1 (6 loads each, per wave)
  stage_a(g, 0, 0, 0); stage_a(g, 0, 0, 1);
  stage_b(g, 0, 0, 0); stage_b(g, 0, 0, 1); stage_b(g, 0, 0, 2); stage_b(g, 0, 0, 3);
  stage_a(g, 1, 1, 0); stage_a(g, 1, 1, 1);
  stage_b(g, 1, 1, 0); stage_b(g, 1, 1, 1); stage_b(g, 1, 1, 2); stage_b(g, 1, 1, 3);
  asm volatile("s_waitcnt vmcnt(6)" ::: "memory");   // tile 0 resident, tile 1 in flight
  __builtin_amdgcn_s_barrier();

  int cur = 0, stg = 2;
#pragma unroll 1
  for (int t = 0; t < 14; ++t) {      // K/64 = 16 tiles; 14 steady-state iters
    tile_step<true, 6>(g, cur, stg, t + 2, acc);
    cur = (cur == 2) ? 0 : cur + 1;
    stg = (stg == 2) ? 0 : stg + 1;
  }
  tile_step<false, 0>(g, cur, 0, 0, acc);   // tile 14 (cur=2): drain tile 15
  tile_step<false, -1>(g, 0, 0, 0, acc);    // tile 15 (cur=0): final
}

// ---------------------------------------------------------------------------
// Fused QKV GEMM.  Grid (64 m, 4 n, 3 z).  z=0: Q (row-major, PRE-SCALED by
// EXPSCALE), z=1: K ([b,h,s,d]), z=2: V ([b,h,d,s]).
// LENGTH SKIP: K/V blocks whose whole 128-row range is >= ceil(len/64)*64
// exit before any staging/barrier (rows never read by attn's key mask).
// ---------------------------------------------------------------------------
__global__ __launch_bounds__(512, 2) void gemm_qkv(
    const u16* __restrict__ A,
    const u16* __restrict__ BtQ, const u16* __restrict__ BtK, const u16* __restrict__ BtV,
    const float* __restrict__ bq, const float* __restrict__ bk, const float* __restrict__ bv,
    const int* __restrict__ lengths,
    u16* __restrict__ Qo, u16* __restrict__ Kt, u16* __restrict__ Vt) {
  __shared__ u16 As[3][AS_T];
  __shared__ u16 Bs[3][BS_T];
  const int z = blockIdx.z;
  const int m0 = blockIdx.x * 128, n0 = blockIdx.y * 256;

  if (z != 0) {
    const int bb = m0 >> 9, s0 = m0 & 511;
    const int kmaxb = (lengths[bb] + 63) & ~63;
    if (s0 >= kmaxb) return;        // dead K/V rows: uniform exit, no barriers yet
  }

  const u16* Bt = (z == 0) ? BtQ : (z == 1) ? BtK : BtV;
  const float* bias = (z == 0) ? bq : (z == 1) ? bk : bv;

  f32x4 acc[4][4];
#pragma unroll
  for (int i = 0; i < 4; ++i)
#pragma unroll
    for (int j = 0; j < 4; ++j) acc[i][j] = f32x4{0.f, 0.f, 0.f, 0.f};

  gemm_core8(A, Bt, &As[0][0], &Bs[0][0], m0, n0, acc);

  const int lane = threadIdx.x & 63, wave = threadIdx.x >> 6;
  const int wm = (wave >> 2) * 64, wn = (wave & 3) * 64;
  const int c = lane & 15, quad = lane >> 4;
#pragma unroll
  for (int ni = 0; ni < 4; ++ni) {
    int n = n0 + wn + ni * 16 + c;
    float bval = bias[n];
#pragma unroll
    for (int mi = 0; mi < 4; ++mi) {
      int mb = m0 + wm + mi * 16 + quad * 4;
      if (z == 2) {
        int bb = mb >> 9, s = mb & 511, hh = n >> 6, d = n & 63;
        ushort4 st;
        st.x = bf16b(acc[mi][ni][0] + bval);
        st.y = bf16b(acc[mi][ni][1] + bval);
        st.z = bf16b(acc[mi][ni][2] + bval);
        st.w = bf16b(acc[mi][ni][3] + bval);
        *(ushort4*)&Vt[(((size_t)(bb * 16 + hh) * 64 + d) << 9) + s] = st;
      } else if (z == 0) {
#pragma unroll
        for (int r = 0; r < 4; ++r) {
          int m = mb + r;
          Qo[(size_t)m * 1024 + n] = bf16b((acc[mi][ni][r] + bval) * EXPSCALE);
        }
      } else {
#pragma unroll
        for (int r = 0; r < 4; ++r) {
          int m = mb + r;
          int bb = m >> 9, s = m & 511, hh = n >> 6, d = n & 63;
          Kt[(((size_t)(bb * 16 + hh) * 512 + s) << 6) + d] = bf16b(acc[mi][ni][r] + bval);
        }
      }
    }
  }
}

// ---------------------------------------------------------------------------
// Output GEMM: C_f32 = A @ Bt^T + bias.  Grid (64 m, 4 n) = 256 blocks.
// ---------------------------------------------------------------------------
__global__ __launch_bounds__(512, 2) void gemm_out(
    const u16* __restrict__ A, const u16* __restrict__ Bt,
    const float* __restrict__ bias, float* __restrict__ Cf) {
  __shared__ u16 As[3][AS_T];
  __shared__ u16 Bs[3][BS_T];
  const int m0 = blockIdx.x * 128, n0 = blockIdx.y * 256;

  f32x4 acc[4][4];
#pragma unroll
  for (int i = 0; i < 4; ++i)
#pragma unroll
    for (int j = 0; j < 4; ++j) acc[i][j] = f32x4{0.f, 0.f, 0.f, 0.f};

  gemm_core8(A, Bt, &As[0][0], &Bs[0][0], m0, n0, acc);

  const int lane = threadIdx.x & 63, wave = threadIdx.x >> 6;
  const int wm = (wave >> 2) * 64, wn = (wave & 3) * 64;
  const int c = lane & 15, quad = lane >> 4;
#pragma unroll
  for (int ni = 0; ni < 4; ++ni) {
    int n = n0 + wn + ni * 16 + c;
    float bval = bias[n];
#pragma unroll
    for (int mi = 0; mi < 4; ++mi) {
#pragma unroll
      for (int r = 0; r < 4; ++r) {
        int m = m0 + wm + mi * 16 + quad * 4 + r;
        Cf[(size_t)m * 1024 + n] = acc[mi][ni][r] + bval;
      }
    }
  }
}

// ---------------------------------------------------------------------------
// Attention v10 (LOCKED, best): zero-shuffle PV via key-permuted staging,
// 16 q-rows/wave, 8 blocks/CU.  Grid (8 qchunks, 16 heads, 16 batches).
// Excursions that REGRESSED or were null (do not retry): dbuf+vmcnt (r3
// +5us), no-LDS direct loads (r13 +15us), VALU-strip/occupancy moves (null).
// ---------------------------------------------------------------------------
__global__ __launch_bounds__(256) void attn_v10(
    const u16* __restrict__ Q, const u16* __restrict__ Kt,
    const u16* __restrict__ Vt, const int* __restrict__ lengths,
    u16* __restrict__ O) {
  const int qc = blockIdx.x, h = blockIdx.y, b = blockIdx.z;
  const int t = threadIdx.x;
  const int lane = t & 63, wave = t >> 6;
  const int c = lane & 15, quad = lane >> 4;
  const int len = lengths[b];
  const int q0 = qc * 64 + wave * 16;           // 16 q-rows per wave

  __shared__ __align__(16) u16 Ks[64 * 64];     // [rho][d], rows key-permuted, d-swizzled
  __shared__ __align__(16) u16 Vs[64 * 64];     // [d][s],  col-chunk swizzled

  const size_t bBase = (size_t)b * (S_SZ * D_SZ);
  const size_t hBase = ((size_t)(b * H_SZ + h)) * (S_SZ * DH_SZ);

  short8 aq0 = *(const short8*)&Q[bBase + (size_t)(q0 + c) * 1024 + h * 64 + quad * 8];
  short8 aq1 = *(const short8*)&Q[bBase + (size_t)(q0 + c) * 1024 + h * 64 + 32 + quad * 8];

  // all-ones bf16 fragment for the row-sum MFMA
  const short ONE = (short)0x3F80;
  const short8 ones = {ONE, ONE, ONE, ONE, ONE, ONE, ONE, ONE};

  // staging lane geometry: 8 rows x 8 chunks per 64-lane wave-group
  const int srow = lane >> 3;                 // row within 8-row group
  const int slc = (lane & 7) ^ srow;          // swizzled logical chunk

  f32x4 o[4];
  f32x4 osum = {0.f, 0.f, 0.f, 0.f};
#pragma unroll
  for (int i = 0; i < 4; ++i) o[i] = f32x4{0.f, 0.f, 0.f, 0.f};

  const int kmax = (len + 63) & ~63;
  for (int k0 = 0; k0 < kmax; k0 += 64) {
    __syncthreads();   // previous iter's LDS reads complete
#pragma unroll
    for (int g = 0; g < 2; ++g) {
      const int grp = wave * 2 + g;
      const int rho = grp * 8 + srow;
      // key-permutation g(rho): rho[4]->key[5], rho[3:2]->key[4:3],
      // rho[5]->key[2], rho[1:0]->key[1:0]
      const int grow = ((rho >> 4) & 1) * 32 + ((rho >> 2) & 3) * 8 +
                       ((rho >> 5) & 1) * 4 + (rho & 3);
      gload_lds16(&Kt[hBase + (size_t)(k0 + grow) * 64 + slc * 8],
                  &Ks[grp * 512]);
      gload_lds16(&Vt[hBase + (size_t)(grp * 8 + srow) * 512 + k0 + slc * 8],
                  &Vs[grp * 512]);
    }
    __syncthreads();   // DMA visible to all waves

    const bool full = (k0 + 64 <= len);       // wave-uniform

#pragma unroll
    for (int half = 0; half < 2; ++half) {    // half == ksub
      u32 pk[4];                              // 4 u32 = 8 bf16 P values
      // --- S^T for sub = half and sub = half+2 (sources of pa(half)) ---
#pragma unroll
      for (int ss = 0; ss < 2; ++ss) {
        const int sub = half + ss * 2;
        const int row = sub * 16 + c;
        short8 bk0 = *(const short8*)&Ks[row * 64 + ((quad ^ (c & 7))) * 8];
        short8 bk1 = *(const short8*)&Ks[row * 64 + (((4 + quad) ^ (c & 7))) * 8];
        // permuted key base for this lane's 4 output rows
        const int keyb = k0 + (sub & 1) * 32 + quad * 8 + (sub >> 1) * 4;
        f32x4 s = {0.f, 0.f, 0.f, 0.f};
        s = __builtin_amdgcn_mfma_f32_16x16x32_bf16(bk0, aq0, s, 0, 0, 0);
        s = __builtin_amdgcn_mfma_f32_16x16x32_bf16(bk1, aq1, s, 0, 0, 0);
        float p0, p1, p2, p3;
        if (full) {
          p0 = exp2f(s[0]); p1 = exp2f(s[1]);
          p2 = exp2f(s[2]); p3 = exp2f(s[3]);
        } else {
          p0 = (keyb + 0) < len ? exp2f(s[0]) : 0.f;
          p1 = (keyb + 1) < len ? exp2f(s[1]) : 0.f;
          p2 = (keyb + 2) < len ? exp2f(s[2]) : 0.f;
          p3 = (keyb + 3) < len ? exp2f(s[3]) : 0.f;
        }
        pk[ss * 2 + 0] = (u32)bf16b(p0) | ((u32)bf16b(p1) << 16);
        pk[ss * 2 + 1] = (u32)bf16b(p2) | ((u32)bf16b(p3) << 16);
      }
      // --- PV for ksub = half: pa from own registers, zero shuffles ---
      u32x4 w0 = {pk[0], pk[1], pk[2], pk[3]};
      short8 pa;
      __builtin_memcpy(&pa, &w0, 16);
      osum = __builtin_amdgcn_mfma_f32_16x16x32_bf16(pa, ones, osum, 0, 0, 0);
#pragma unroll
      for (int dt = 0; dt < 4; ++dt) {
        const int vrow = dt * 16 + c;
        short8 vb = *(const short8*)&Vs[vrow * 64 + (((half * 4 + quad) ^ (c & 7))) * 8];
        o[dt] = __builtin_amdgcn_mfma_f32_16x16x32_bf16(pa, vb, o[dt], 0, 0, 0);
      }
    }
  }

  // --- epilogue: osum[r] is the row-sum for exactly the q-row of o[dt][r]
  //     (same accumulator layout) -> direct divide. ---
  float inv[4];
#pragma unroll
  for (int r = 0; r < 4; ++r) inv[r] = 1.0f / osum[r];
#pragma unroll
  for (int dt = 0; dt < 4; ++dt) {
#pragma unroll
    for (int r = 0; r < 4; ++r) {
      int s = q0 + quad * 4 + r;
      float val = o[dt][r] * inv[r];
      O[bBase + (size_t)s * 1024 + h * 64 + dt * 16 + c] = bf16b(val);
    }
  }
}

// ---------------------------------------------------------------------------
extern "C" void kernel_launch(void* const* d_in, const int* in_sizes, int n_in,
                              void* d_out, int out_size, void* d_ws, size_t ws_size,
                              hipStream_t stream) {
  const float* v  = (const float*)d_in[0];
  const int* lengths = (const int*)d_in[1];
  const float* Wq = (const float*)d_in[2];
  const float* bq = (const float*)d_in[3];
  const float* Wk = (const float*)d_in[4];
  const float* bk = (const float*)d_in[5];
  const float* Wv = (const float*)d_in[6];
  const float* bv = (const float*)d_in[7];
  const float* Wo = (const float*)d_in[8];
  const float* bo = (const float*)d_in[9];

  char* ws = (char*)d_ws;
  const size_t TSZ = (size_t)M_SZ * D_SZ * 2;   // 16 MiB bf16 activation tensor
  const size_t WSZ = (size_t)1 << 21;           // 2 MiB per transposed weight
  u16* vB  = (u16*)(ws);                        // aliased: AO reuses this after QKV
  u16* AO  = vB;
  u16* WqT = (u16*)(ws + TSZ + 0 * WSZ);
  u16* WkT = (u16*)(ws + TSZ + 1 * WSZ);
  u16* WvT = (u16*)(ws + TSZ + 2 * WSZ);
  u16* WoT = (u16*)(ws + TSZ + 3 * WSZ);
  u16* Qb  = (u16*)(ws + TSZ + 4 * WSZ + 0 * TSZ);
  u16* Kt  = (u16*)(ws + TSZ + 4 * WSZ + 1 * TSZ);
  u16* Vt  = (u16*)(ws + TSZ + 4 * WSZ + 2 * TSZ);

  prep<<<dim3(8192 + 4096), 256, 0, stream>>>(v, vB, Wq, Wk, Wv, Wo, WqT, WkT, WvT, WoT);

  gemm_qkv<<<dim3(64, 4, 3), 512, 0, stream>>>(vB, WqT, WkT, WvT, bq, bk, bv, lengths, Qb, Kt, Vt);

  attn_v10<<<dim3(8, 16, 16), 256, 0, stream>>>(Qb, Kt, Vt, lengths, AO);

  gemm_out<<<dim3(64, 4), 512, 0, stream>>>(AO, WoT, bo, (float*)d_out);
}